// Round 11
// baseline (999.276 us; speedup 1.0000x reference)
//
#include <hip/hip_runtime.h>

typedef __attribute__((ext_vector_type(8))) short short8v;
typedef __attribute__((ext_vector_type(4))) float f32x4;

#define B_ 32
#define C_ 128
#define J_ 24
#define T_ 128
#define Q_ 6
#define K_ 1024
#define JT (J_*T_)          // 3072
#define M_ (B_*JT)          // 98304
#define NBLK 768            // M_/128 rows per block (8 waves x 16 rows)

#define OUT_QUANT 0
#define OUT_IDX   12582912
#define OUT_LOSS  13172736
#define OUT_PERP  13172737

#define TAU_S 0.01f   // s-space tie window (= 0.02 in d-space); round-6/9/10-proven

__device__ __forceinline__ unsigned short f2bf(float f) {
    unsigned int u = __float_as_uint(f);
    u = (u + 0x7FFFu + ((u >> 16) & 1u)) >> 16;
    return (unsigned short)u;
}
__device__ __forceinline__ float bf2f(unsigned short h) {
    return __uint_as_float(((unsigned int)h) << 16);
}

__device__ __forceinline__ void gload16(const void* g, void* lds) {
    __builtin_amdgcn_global_load_lds(
        (const __attribute__((address_space(1))) void*)g,
        (__attribute__((address_space(3))) void*)lds, 16, 0, 0);
}

// ---------------- c2: per-code squared norms (fp32 codebook) ----------------
__global__ __launch_bounds__(256) void c2_kernel(const float* __restrict__ cb,
                                                 float* __restrict__ c2) {
    int wave = (blockIdx.x * blockDim.x + threadIdx.x) >> 6;
    int lane = threadIdx.x & 63;
    if (wave >= Q_ * K_) return;
    const float2 v = reinterpret_cast<const float2*>(cb + (size_t)wave * C_)[lane];
    float s = v.x * v.x + v.y * v.y;
    #pragma unroll
    for (int off = 32; off; off >>= 1) s += __shfl_down(s, off, 64);
    if (lane == 0) c2[wave] = s;
}

// ---------------- codebook -> tiled/swizzled bf16 hi/lo LDS-image layout ----------------
__global__ __launch_bounds__(256) void cbtile_kernel(const float* __restrict__ cb,
                                                     unsigned short* __restrict__ cbt) {
    int i = blockIdx.x * 256 + threadIdx.x;
    if (i >= Q_ * 32 * 1024) return;
    int q = i >> 15;
    int rem = i & 32767;
    int tau = rem >> 10;
    int slot = rem & 1023;
    int part = slot >> 9;
    int ks = (slot >> 7) & 3;
    int nt = (slot >> 6) & 1;
    int r6 = slot & 63;
    int a = (r6 >> 4) & 3;
    int b3 = (r6 >> 3) & 1;
    int low3 = r6 & 7;
    int c4 = (b3 << 3) | (low3 ^ a);
    int code = tau * 32 + nt * 16 + c4;
    const float* src = cb + ((size_t)q * K_ + code) * C_ + ks * 32 + a * 8;
    short8v v;
    #pragma unroll
    for (int j = 0; j < 8; ++j) {
        float f = src[j];
        unsigned short hh = f2bf(f);
        v[j] = (part == 0) ? (short)hh : (short)f2bf(f - bf2f(hh));
    }
    *(short8v*)(cbt + (size_t)i * 8) = v;
}

// ---------------- transpose x (B,C,J,T) -> res (M,C) ----------------
__global__ __launch_bounds__(256) void transpose_kernel(const float* __restrict__ x,
                                                        float* __restrict__ res) {
    __shared__ float tile[32][33];
    const int tx = threadIdx.x & 31, ty = threadIdx.x >> 5;
    const int jt0 = blockIdx.x * 32;
    const int c0 = blockIdx.y * 32;
    const int b = blockIdx.z;
    const float* xb = x + ((size_t)b * C_ + c0) * JT + jt0;
    #pragma unroll
    for (int i = 0; i < 4; ++i) {
        int cc = ty + 8 * i;
        tile[cc][tx] = xb[(size_t)cc * JT + tx];
    }
    __syncthreads();
    float* rb = res + ((size_t)b * JT + jt0) * C_ + c0;
    #pragma unroll
    for (int i = 0; i < 4; ++i) {
        int jj = ty + 8 * i;
        rb[(size_t)jj * C_ + tx] = tile[tx][jj];
    }
}

// ---------------- fused ALL-STAGES VQ: 8 waves/block, 16 rows/wave, ring-3 ----------------
__global__ __launch_bounds__(512, 2) void vq_fused_kernel(
        float* __restrict__ res,                 // in: transposed x; out: quantized (M,C)
        const float* __restrict__ cb,
        const unsigned short* __restrict__ cbt,
        const float* __restrict__ c2g,
        int* __restrict__ idxws, int* __restrict__ counts,
        float* __restrict__ partials) {
    __shared__ __attribute__((aligned(16))) unsigned short bsA[8192]; // 16 KB
    __shared__ __attribute__((aligned(16))) unsigned short bsB[8192];
    __shared__ __attribute__((aligned(16))) unsigned short bsC[8192];
    __shared__ int idx_lds[128];
    __shared__ int nflag[8];
    __shared__ int flagl[8][16];
    __shared__ float wsum[8];
    __shared__ __attribute__((aligned(16))) float rowbuf[8][128];

    const int t = threadIdx.x;
    const int w = t >> 6, l = t & 63;       // w in 0..7
    const int la = l >> 4;                  // 0..3
    const int lc = l & 15;
    const int rowbase = blockIdx.x * 128 + w * 16;
    const int lb = la * 256 + (l & 8) * 16 + (((l & 7) ^ la) * 16); // frag-read byte base

    // ---- 16 residual rows/wave -> registers (row lc, cols la*8 + ks*32 + j) ----
    float rres[32];
    {
        const float* ap = res + (size_t)(rowbase + lc) * C_ + la * 8;
        #pragma unroll
        for (int ks = 0; ks < 4; ++ks) {
            float4 f0 = *(const float4*)(ap + ks * 32);
            float4 f1 = *(const float4*)(ap + ks * 32 + 4);
            rres[ks * 8 + 0] = f0.x; rres[ks * 8 + 1] = f0.y;
            rres[ks * 8 + 2] = f0.z; rres[ks * 8 + 3] = f0.w;
            rres[ks * 8 + 4] = f1.x; rres[ks * 8 + 5] = f1.y;
            rres[ks * 8 + 6] = f1.z; rres[ks * 8 + 7] = f1.w;
        }
    }

// 8 waves split the 16 KB tile: each wave stages 2 KB (2 x gload16 per lane)
#define STAGE(base_, tau_, buf_) { \
        const unsigned short* sp = (base_) + (size_t)(tau_) * 8192 + w * 1024 + l * 8; \
        char* dp = ((char*)(buf_)) + w * 2048; \
        gload16(sp, dp); \
        gload16(sp + 512, dp + 1024); \
    }

    for (int q = 0; q < Q_; ++q) {
        const int qk0 = q * K_;
        const unsigned short* cbase = cbt + (size_t)q * (32 * 8192);
        if (l == 0) nflag[w] = 0;

        // ---- c2 for tau=0 (issued before STAGEs; drained by prologue vmcnt(2)) ----
        float c2r0 = c2g[qk0 + lc];
        float c2r1 = c2g[qk0 + 16 + lc];

        // ---- stage tiles 0,1 ----
        STAGE(cbase, 0, bsA)
        STAGE(cbase, 1, bsB)

        // ---- A-frags: rres -> bf16 hi/lo (hides under staging) ----
        short8v ah[4], al[4];
        #pragma unroll
        for (int ks = 0; ks < 4; ++ks) {
            short8v vh, vl;
            #pragma unroll
            for (int j = 0; j < 8; ++j) {
                float v = rres[ks * 8 + j];
                unsigned short hh = f2bf(v);
                vh[j] = (short)hh;
                vl[j] = (short)f2bf(v - bf2f(hh));
            }
            ah[ks] = vh;
            al[ks] = vl;
        }

        float bsv[4], bs2[4];
        int bi[4];
        #pragma unroll
        for (int rg = 0; rg < 4; ++rg) {
            bsv[rg] = -3.4e38f; bs2[rg] = -3.4e38f; bi[rg] = 0;
        }

        // drain c2 + tile0 (tile1's 2 loads may stay in flight)
        asm volatile("s_waitcnt vmcnt(2)" ::: "memory");
        __builtin_amdgcn_s_barrier();
        float c2n0 = -0.5f * c2r0;
        float c2n1 = -0.5f * c2r1;

        const char* bcur = (const char*)bsA;
        const char* bnx1 = (const char*)bsB;
        const char* bnx2 = (const char*)bsC;

        // ---- main loop: c2(τ+1) + STAGE(τ+2) issue, compute τ, counted drain ----
        for (int tau = 0; tau < 32; ++tau) {
            if (tau < 31) {
                c2r0 = c2g[qk0 + (tau + 1) * 32 + lc];
                c2r1 = c2g[qk0 + (tau + 1) * 32 + 16 + lc];
            }
            if (tau < 30) STAGE(cbase, tau + 2, (void*)bnx2)

            #pragma unroll
            for (int nt = 0; nt < 2; ++nt) {
                const int code = tau * 32 + nt * 16 + lc;
                const float cinit = nt ? c2n1 : c2n0;
                f32x4 aA = {cinit, cinit, cinit, cinit};
                f32x4 aB = {0.f, 0.f, 0.f, 0.f};
                f32x4 aC = {0.f, 0.f, 0.f, 0.f};
                #pragma unroll
                for (int ks = 0; ks < 4; ++ks) {
                    const char* bb = bcur + ks * 2048 + nt * 1024 + lb;
                    const short8v bh = *(const short8v*)(bb);
                    const short8v bl = *(const short8v*)(bb + 8192);
                    aA = __builtin_amdgcn_mfma_f32_16x16x32_bf16(ah[ks], bh, aA, 0, 0, 0);
                    aB = __builtin_amdgcn_mfma_f32_16x16x32_bf16(al[ks], bh, aB, 0, 0, 0);
                    aC = __builtin_amdgcn_mfma_f32_16x16x32_bf16(ah[ks], bl, aC, 0, 0, 0);
                }
                // argmax of s = dot - c2/2; first-wins strict >
#define UPD(rg) { \
                float v = (aA[rg] + aB[rg]) + aC[rg]; \
                bs2[rg] = fmaxf(bs2[rg], fminf(bsv[rg], v)); \
                bool gt = v > bsv[rg]; \
                bsv[rg] = fmaxf(bsv[rg], v); \
                bi[rg] = gt ? code : bi[rg]; }
                UPD(0) UPD(1) UPD(2) UPD(3)
#undef UPD
            }

            // counted drain: tile τ+1 (and this τ's c2 loads) resident after this
            if (tau < 30) {
                asm volatile("s_waitcnt vmcnt(4)" ::: "memory");
            } else if (tau == 30) {
                asm volatile("s_waitcnt vmcnt(2)" ::: "memory");
            } else {
                asm volatile("s_waitcnt vmcnt(0)" ::: "memory");
            }
            __builtin_amdgcn_s_barrier();
            c2n0 = -0.5f * c2r0;
            c2n1 = -0.5f * c2r1;
            const char* tmp = bcur; bcur = bnx1; bnx1 = bnx2; bnx2 = tmp;
        }

        // ---- per-wave cross-lane argmax reduce (16 code-lanes per row) ----
        #pragma unroll
        for (int rg = 0; rg < 4; ++rg) {
            float s1 = bsv[rg], s2 = bs2[rg];
            int i1 = bi[rg];
            #pragma unroll
            for (int off = 1; off < 16; off <<= 1) {
                float os1 = __shfl_xor(s1, off);
                float os2 = __shfl_xor(s2, off);
                int oi1 = __shfl_xor(i1, off);
                float ns2 = fmaxf(fmaxf(s2, os2), fminf(s1, os1));
                if (os1 > s1 || (os1 == s1 && oi1 < i1)) { s1 = os1; i1 = oi1; }
                s2 = ns2;
            }
            if (lc == 0) {
                const int rr = la * 4 + rg;      // row within wave, 0..15
                idx_lds[w * 16 + rr] = i1;
                if (s1 - s2 < TAU_S) {
                    int p = atomicAdd(&nflag[w], 1);
                    flagl[w][p] = rr;
                }
            }
        }

        // ---- fp64 refinement (wave-local, rare); row shared via LDS rowbuf ----
        {
            const int nf = nflag[w];
            for (int f = 0; f < nf; ++f) {
                const int rr = flagl[w][f];
                if (lc == rr) {
                    #pragma unroll
                    for (int ks = 0; ks < 4; ++ks) {
                        #pragma unroll
                        for (int j = 0; j < 8; ++j)
                            rowbuf[w][la * 8 + ks * 32 + j] = rres[ks * 8 + j];
                    }
                }
                asm volatile("s_waitcnt lgkmcnt(0)" ::: "memory");
                __builtin_amdgcn_sched_barrier(0);
                const float4* rf4 = (const float4*)&rowbuf[w][0];
                double bdd = 1e300;
                int bk = 0;
                for (int kk = 0; kk < 16; ++kk) {
                    const int k = l + kk * 64;
                    const float4* bp4 = (const float4*)(cb + ((size_t)qk0 + k) * C_);
                    double s = 0.0;
                    for (int c4 = 0; c4 < 32; ++c4) {
                        float4 bv = bp4[c4];
                        float4 rv = rf4[c4];
                        double d0 = (double)rv.x - (double)bv.x; s = fma(d0, d0, s);
                        double d1 = (double)rv.y - (double)bv.y; s = fma(d1, d1, s);
                        double d2 = (double)rv.z - (double)bv.z; s = fma(d2, d2, s);
                        double d3 = (double)rv.w - (double)bv.w; s = fma(d3, d3, s);
                    }
                    if (s < bdd || (s == bdd && k < bk)) { bdd = s; bk = k; }
                }
                #pragma unroll
                for (int off = 1; off < 64; off <<= 1) {
                    double od = __shfl_xor(bdd, off);
                    int ok = __shfl_xor(bk, off);
                    if (od < bdd || (od == bdd && ok < bk)) { bdd = od; bk = ok; }
                }
                if (l == 0) idx_lds[w * 16 + rr] = bk;
                asm volatile("s_waitcnt lgkmcnt(0)" ::: "memory");
            }
        }

        // ---- idx out + histogram (one row per lane, 16 rows/wave) ----
        if (l < 16) {
            const int k0 = idx_lds[w * 16 + l];
            idxws[(size_t)q * M_ + rowbase + l] = k0;
            atomicAdd(&counts[qk0 + k0], 1);
        }

        // ---- in-register residual update + loss partial ----
        float sq = 0.f;
        {
            const int k = idx_lds[w * 16 + lc];
            const float* cbr = cb + ((size_t)qk0 + k) * C_ + la * 8;
            #pragma unroll
            for (int ks = 0; ks < 4; ++ks) {
                float4 cv0 = *(const float4*)(cbr + ks * 32);
                float4 cv1 = *(const float4*)(cbr + ks * 32 + 4);
                float cvv[8] = {cv0.x, cv0.y, cv0.z, cv0.w, cv1.x, cv1.y, cv1.z, cv1.w};
                #pragma unroll
                for (int j = 0; j < 8; ++j) {
                    float rv = rres[ks * 8 + j];
                    float cvj = cvv[j];
                    float dd = rv - cvj;
                    sq += dd * dd;
                    // STE rounding: quant = r + (xd - r); new_res = r - quant
                    rres[ks * 8 + j] = rv - (rv + (cvj - rv));
                }
            }
        }
        #pragma unroll
        for (int off = 32; off; off >>= 1) sq += __shfl_down(sq, off, 64);
        if (l == 0) wsum[w] = sq;
        __syncthreads();
        if (t == 0) {
            float ssum = 0.f;
            #pragma unroll
            for (int ww = 0; ww < 8; ++ww) ssum += wsum[ww];
            partials[q * NBLK + blockIdx.x] = ssum;
        }
        __syncthreads();
    }

    // ---- epilogue: quant = initial - final residual, in-place over res ----
    {
        float* ap = res + (size_t)(rowbase + lc) * C_ + la * 8;
        #pragma unroll
        for (int ks = 0; ks < 4; ++ks) {
            float4 f0 = *(const float4*)(ap + ks * 32);
            float4 f1 = *(const float4*)(ap + ks * 32 + 4);
            float4 o0, o1;
            o0.x = f0.x - rres[ks * 8 + 0];
            o0.y = f0.y - rres[ks * 8 + 1];
            o0.z = f0.z - rres[ks * 8 + 2];
            o0.w = f0.w - rres[ks * 8 + 3];
            o1.x = f1.x - rres[ks * 8 + 4];
            o1.y = f1.y - rres[ks * 8 + 5];
            o1.z = f1.z - rres[ks * 8 + 6];
            o1.w = f1.w - rres[ks * 8 + 7];
            *(float4*)(ap + ks * 32) = o0;
            *(float4*)(ap + ks * 32 + 4) = o1;
        }
    }
#undef STAGE
}

// ---------------- scalars: loss + perplexity ----------------
__global__ __launch_bounds__(256) void scalars_kernel(const float* __restrict__ partials,
                                                      const int* __restrict__ counts,
                                                      float* __restrict__ out) {
    __shared__ float red[256];
    const int t = threadIdx.x;
    float loss_acc = 0.f, perp_acc = 0.f;
    for (int q = 0; q < Q_; ++q) {
        float s = 0.f;
        for (int i = t; i < NBLK; i += 256) s += partials[q * NBLK + i];
        red[t] = s;
        __syncthreads();
        for (int o = 128; o; o >>= 1) {
            if (t < o) red[t] += red[t + o];
            __syncthreads();
        }
        if (t == 0) loss_acc += red[0] / (float)(M_ * C_);
        __syncthreads();
    }
    for (int q = 0; q < Q_; ++q) {
        float s = 0.f;
        for (int k = t; k < K_; k += 256) {
            float p = (float)counts[q * K_ + k] / (float)M_;
            s += p * logf(p + 1e-10f);
        }
        red[t] = s;
        __syncthreads();
        for (int o = 128; o; o >>= 1) {
            if (t < o) red[t] += red[t + o];
            __syncthreads();
        }
        if (t == 0) perp_acc += expf(-red[0]);
        __syncthreads();
    }
    if (t == 0) {
        out[OUT_LOSS] = loss_acc / (float)Q_;
        out[OUT_PERP] = perp_acc / (float)Q_;
    }
}

// ---------------- quant (M,C) -> out (B,C,J,T) transpose ----------------
__global__ __launch_bounds__(256) void finalt_kernel(const float* __restrict__ qout,
                                                     float* __restrict__ out) {
    __shared__ float tile[32][33];
    const int tx = threadIdx.x & 31, ty = threadIdx.x >> 5;
    const int jt0 = blockIdx.x * 32;
    const int c0 = blockIdx.y * 32;
    const int b = blockIdx.z;
    const float* qb = qout + ((size_t)b * JT + jt0) * C_ + c0;
    #pragma unroll
    for (int i = 0; i < 4; ++i) {
        int jj = ty + 8 * i;
        tile[jj][tx] = qb[(size_t)jj * C_ + tx];
    }
    __syncthreads();
    float* ob = out + ((size_t)b * C_ + c0) * JT + jt0;
    #pragma unroll
    for (int i = 0; i < 4; ++i) {
        int cc = ty + 8 * i;
        ob[(size_t)cc * JT + tx] = tile[tx][cc];
    }
}

// ---------------- indices (B,J,T,Q) as float ----------------
__global__ __launch_bounds__(256) void idxout_kernel(const int* __restrict__ idxin,
                                                     float* __restrict__ out) {
    int f = blockIdx.x * 256 + threadIdx.x;
    if (f >= M_ * Q_) return;
    int m = f / Q_;
    int q = f - m * Q_;
    out[f] = (float)idxin[q * M_ + m];
}

extern "C" void kernel_launch(void* const* d_in, const int* in_sizes, int n_in,
                              void* d_out, int out_size, void* d_ws, size_t ws_size,
                              hipStream_t stream) {
    const float* x = (const float*)d_in[0];
    const float* cb = (const float*)d_in[1];
    float* out = (float*)d_out;
    char* ws = (char*)d_ws;

    float* res = (float*)ws;                               // 50,331,648 B (in: x^T, out: quant)
    int* idxws = (int*)(ws + 50331648);                    //  2,359,296 B
    float* c2 = (float*)(ws + 52690944);                   //     24,576 B
    int* counts = (int*)(ws + 52715520);                   //     24,576 B
    float* partials = (float*)(ws + 52740096);             //     18,432 B
    unsigned short* cbt = (unsigned short*)(ws + 52758528);// 3,145,728 B

    hipMemsetAsync(counts, 0, Q_ * K_ * sizeof(int), stream);
    c2_kernel<<<1536, 256, 0, stream>>>(cb, c2);
    cbtile_kernel<<<768, 256, 0, stream>>>(cb, cbt);
    transpose_kernel<<<dim3(96, 4, 32), 256, 0, stream>>>(x, res);
    vq_fused_kernel<<<NBLK, 512, 0, stream>>>(res, cb, cbt, c2, idxws, counts, partials);
    scalars_kernel<<<1, 256, 0, stream>>>(partials, counts, out);
    finalt_kernel<<<dim3(96, 4, 32), 256, 0, stream>>>(res, out);
    idxout_kernel<<<2304, 256, 0, stream>>>(idxws, out + OUT_IDX);
}

// Round 12
// 767.159 us; speedup vs baseline: 1.3026x; 1.3026x over previous
//
#include <hip/hip_runtime.h>

typedef __attribute__((ext_vector_type(8))) short short8v;
typedef __attribute__((ext_vector_type(4))) float f32x4;

#define B_ 32
#define C_ 128
#define J_ 24
#define T_ 128
#define Q_ 6
#define K_ 1024
#define JT (J_*T_)          // 3072
#define M_ (B_*JT)          // 98304
#define NBLK 768            // M_/128 rows per block

#define OUT_QUANT 0
#define OUT_IDX   12582912
#define OUT_LOSS  13172736
#define OUT_PERP  13172737

#define TAU 0.008f   // d-space tie window; hi/lo-bf16 MFMA 6-sigma error ~2.4e-3 -> 3x margin

__device__ __forceinline__ unsigned short f2bf(float f) {
    unsigned int u = __float_as_uint(f);
    u = (u + 0x7FFFu + ((u >> 16) & 1u)) >> 16;
    return (unsigned short)u;
}
__device__ __forceinline__ float bf2f(unsigned short h) {
    return __uint_as_float(((unsigned int)h) << 16);
}

__device__ __forceinline__ void gload16(const void* g, void* lds) {
    __builtin_amdgcn_global_load_lds(
        (const __attribute__((address_space(1))) void*)g,
        (__attribute__((address_space(3))) void*)lds, 16, 0, 0);
}

// ---------------- c2: per-code squared norms (fp32 codebook) ----------------
__global__ __launch_bounds__(256) void c2_kernel(const float* __restrict__ cb,
                                                 float* __restrict__ c2) {
    int wave = (blockIdx.x * blockDim.x + threadIdx.x) >> 6;
    int lane = threadIdx.x & 63;
    if (wave >= Q_ * K_) return;
    const float2 v = reinterpret_cast<const float2*>(cb + (size_t)wave * C_)[lane];
    float s = v.x * v.x + v.y * v.y;
    #pragma unroll
    for (int off = 32; off; off >>= 1) s += __shfl_down(s, off, 64);
    if (lane == 0) c2[wave] = s;
}

// ---------------- codebook -> tiled/swizzled bf16 hi/lo LDS-image layout ----------------
__global__ __launch_bounds__(256) void cbtile_kernel(const float* __restrict__ cb,
                                                     unsigned short* __restrict__ cbt) {
    int i = blockIdx.x * 256 + threadIdx.x;
    if (i >= Q_ * 32 * 1024) return;
    int q = i >> 15;
    int rem = i & 32767;
    int tau = rem >> 10;
    int slot = rem & 1023;
    int part = slot >> 9;
    int ks = (slot >> 7) & 3;
    int nt = (slot >> 6) & 1;
    int r6 = slot & 63;
    int a = (r6 >> 4) & 3;
    int b3 = (r6 >> 3) & 1;
    int low3 = r6 & 7;
    int c4 = (b3 << 3) | (low3 ^ a);
    int code = tau * 32 + nt * 16 + c4;
    const float* src = cb + ((size_t)q * K_ + code) * C_ + ks * 32 + a * 8;
    short8v v;
    #pragma unroll
    for (int j = 0; j < 8; ++j) {
        float f = src[j];
        unsigned short hh = f2bf(f);
        v[j] = (part == 0) ? (short)hh : (short)f2bf(f - bf2f(hh));
    }
    *(short8v*)(cbt + (size_t)i * 8) = v;
}

// ---------------- transpose x (B,C,J,T) -> res (M,C) ----------------
__global__ __launch_bounds__(256) void transpose_kernel(const float* __restrict__ x,
                                                        float* __restrict__ res) {
    __shared__ float tile[32][33];
    const int tx = threadIdx.x & 31, ty = threadIdx.x >> 5;
    const int jt0 = blockIdx.x * 32;
    const int c0 = blockIdx.y * 32;
    const int b = blockIdx.z;
    const float* xb = x + ((size_t)b * C_ + c0) * JT + jt0;
    #pragma unroll
    for (int i = 0; i < 4; ++i) {
        int cc = ty + 8 * i;
        tile[cc][tx] = xb[(size_t)cc * JT + tx];
    }
    __syncthreads();
    float* rb = res + ((size_t)b * JT + jt0) * C_ + c0;
    #pragma unroll
    for (int i = 0; i < 4; ++i) {
        int jj = ty + 8 * i;
        rb[(size_t)jj * C_ + tx] = tile[tx][jj];
    }
}

// ---------------- fused ALL-STAGES VQ: 2-tau phases, ring-4, residual in regs ----------------
__global__ __launch_bounds__(256, 2) void vq_fused_kernel(
        float* __restrict__ res,                 // in: transposed x; out: quantized (M,C)
        const float* __restrict__ cb,
        const unsigned short* __restrict__ cbt,
        const float* __restrict__ c2g,
        int* __restrict__ idxws, int* __restrict__ counts,
        float* __restrict__ partials) {
    __shared__ __attribute__((aligned(16))) unsigned short bs[4][8192]; // 4 x 16 KB ring
    __shared__ int idx_lds[128];
    __shared__ int nflag[4];
    __shared__ int flagl[4][32];
    __shared__ float wsum[4];
    __shared__ __attribute__((aligned(16))) float rowbuf[4][128];

    const int t = threadIdx.x;
    const int w = t >> 6, l = t & 63;
    const int la = l >> 4;        // 0..3
    const int lc = l & 15;
    const int rowbase = blockIdx.x * 128 + w * 32;
    const int lb = la * 256 + (l & 8) * 16 + (((l & 7) ^ la) * 16); // frag-read byte base

    // ---- residual rows -> registers ----
    float rres[64];
    #pragma unroll
    for (int mf = 0; mf < 2; ++mf) {
        const float* ap = res + (size_t)(rowbase + mf * 16 + lc) * C_ + la * 8;
        #pragma unroll
        for (int ks = 0; ks < 4; ++ks) {
            float4 f0 = *(const float4*)(ap + ks * 32);
            float4 f1 = *(const float4*)(ap + ks * 32 + 4);
            rres[mf * 32 + ks * 8 + 0] = f0.x; rres[mf * 32 + ks * 8 + 1] = f0.y;
            rres[mf * 32 + ks * 8 + 2] = f0.z; rres[mf * 32 + ks * 8 + 3] = f0.w;
            rres[mf * 32 + ks * 8 + 4] = f1.x; rres[mf * 32 + ks * 8 + 5] = f1.y;
            rres[mf * 32 + ks * 8 + 6] = f1.z; rres[mf * 32 + ks * 8 + 7] = f1.w;
        }
    }

#define STAGE(base_, tau_) { \
        const unsigned short* sp = (base_) + (size_t)(tau_) * 8192 + w * 2048 + l * 8; \
        char* dp = ((char*)bs[(tau_) & 3]) + w * 4096; \
        gload16(sp, dp); \
        gload16(sp + 512, dp + 1024); \
        gload16(sp + 1024, dp + 2048); \
        gload16(sp + 1536, dp + 3072); \
    }

    for (int q = 0; q < Q_; ++q) {
        const int qk0 = q * K_;
        const unsigned short* cbase = cbt + (size_t)q * (32 * 8192);
        if (l == 0) nflag[w] = 0;

        // ---- prologue: stage tiles 0..3, c2 for taus 0,1 ----
        STAGE(cbase, 0)
        STAGE(cbase, 1)
        STAGE(cbase, 2)
        STAGE(cbase, 3)
        float c2v0 = c2g[qk0 + lc];
        float c2v1 = c2g[qk0 + 16 + lc];
        float c2v2 = c2g[qk0 + 32 + lc];
        float c2v3 = c2g[qk0 + 48 + lc];

        // ---- A-frags: rres -> bf16 hi/lo (VALU, overlaps staging) ----
        short8v ah[2][4], al[2][4];
        #pragma unroll
        for (int mf = 0; mf < 2; ++mf) {
            #pragma unroll
            for (int ks = 0; ks < 4; ++ks) {
                short8v vh, vl;
                #pragma unroll
                for (int j = 0; j < 8; ++j) {
                    float v = rres[mf * 32 + ks * 8 + j];
                    unsigned short hh = f2bf(v);
                    vh[j] = (short)hh;
                    vl[j] = (short)f2bf(v - bf2f(hh));
                }
                ah[mf][ks] = vh;
                al[mf][ks] = vl;
            }
        }

        float bd[2][4], bd2[2][4];
        int bi[2][4];
        #pragma unroll
        for (int mf = 0; mf < 2; ++mf)
            #pragma unroll
            for (int rg = 0; rg < 4; ++rg) {
                bd[mf][rg] = 3.4e38f; bd2[mf][rg] = 3.4e38f; bi[mf][rg] = 0;
            }

        asm volatile("s_waitcnt vmcnt(0)" ::: "memory");
        __builtin_amdgcn_s_barrier();

        // ---- main loop: 16 phases of 2 taus; one barrier per phase ----
        for (int p = 0; p < 16; ++p) {
            // issue next-phase staging + c2 first (flies under compute)
            if (p < 15) {
                STAGE(cbase, 2 * p + 2)
                STAGE(cbase, 2 * p + 3)
            }
            float n0 = 0.f, n1 = 0.f, n2 = 0.f, n3 = 0.f;
            if (p < 15) {
                n0 = c2g[qk0 + (2 * p + 2) * 32 + lc];
                n1 = c2g[qk0 + (2 * p + 2) * 32 + 16 + lc];
                n2 = c2g[qk0 + (2 * p + 3) * 32 + lc];
                n3 = c2g[qk0 + (2 * p + 3) * 32 + 16 + lc];
            }

            #pragma unroll
            for (int tt = 0; tt < 2; ++tt) {
                const int tau = 2 * p + tt;
                const char* bufp = (const char*)bs[tau & 3];
                #pragma unroll
                for (int nt = 0; nt < 2; ++nt) {
                    const int code = tau * 32 + nt * 16 + lc;
                    const float c2v = tt ? (nt ? c2v3 : c2v2) : (nt ? c2v1 : c2v0);
                    f32x4 aA0 = {0.f, 0.f, 0.f, 0.f}, aM0 = aA0, aA1 = aA0, aM1 = aA0;
                    #pragma unroll
                    for (int ks = 0; ks < 4; ++ks) {
                        const char* bb = bufp + ks * 2048 + nt * 1024 + lb;
                        const short8v bh = *(const short8v*)(bb);
                        const short8v bl = *(const short8v*)(bb + 8192);
                        aA0 = __builtin_amdgcn_mfma_f32_16x16x32_bf16(ah[0][ks], bh, aA0, 0, 0, 0);
                        aM0 = __builtin_amdgcn_mfma_f32_16x16x32_bf16(al[0][ks], bh, aM0, 0, 0, 0);
                        aM0 = __builtin_amdgcn_mfma_f32_16x16x32_bf16(ah[0][ks], bl, aM0, 0, 0, 0);
                        aA1 = __builtin_amdgcn_mfma_f32_16x16x32_bf16(ah[1][ks], bh, aA1, 0, 0, 0);
                        aM1 = __builtin_amdgcn_mfma_f32_16x16x32_bf16(al[1][ks], bh, aM1, 0, 0, 0);
                        aM1 = __builtin_amdgcn_mfma_f32_16x16x32_bf16(ah[1][ks], bl, aM1, 0, 0, 0);
                    }
#define UPD(A, Mv, mf, rg) { \
                    float s = A[rg] + Mv[rg]; \
                    float d = fmaf(-2.f, s, c2v); \
                    bool lt = d < bd[mf][rg]; \
                    bd2[mf][rg] = lt ? bd[mf][rg] : fminf(bd2[mf][rg], d); \
                    bd[mf][rg] = lt ? d : bd[mf][rg]; \
                    bi[mf][rg] = lt ? code : bi[mf][rg]; }
                    UPD(aA0, aM0, 0, 0) UPD(aA0, aM0, 0, 1) UPD(aA0, aM0, 0, 2) UPD(aA0, aM0, 0, 3)
                    UPD(aA1, aM1, 1, 0) UPD(aA1, aM1, 1, 1) UPD(aA1, aM1, 1, 2) UPD(aA1, aM1, 1, 3)
#undef UPD
                }
            }

            if (p < 15) {
                // drain this phase's 8 stage loads (4 c2 loads may remain in flight)
                asm volatile("s_waitcnt vmcnt(4)" ::: "memory");
                __builtin_amdgcn_s_barrier();
                c2v0 = n0; c2v1 = n1; c2v2 = n2; c2v3 = n3;  // c2 use auto-waits
            }
        }

        // ---- per-wave cross-lane argmin reduce ----
        #pragma unroll
        for (int mf = 0; mf < 2; ++mf) {
            #pragma unroll
            for (int rg = 0; rg < 4; ++rg) {
                float d1 = bd[mf][rg], d2 = bd2[mf][rg];
                int i1 = bi[mf][rg];
                #pragma unroll
                for (int off = 1; off < 16; off <<= 1) {
                    float od1 = __shfl_xor(d1, off);
                    float od2 = __shfl_xor(d2, off);
                    int oi1 = __shfl_xor(i1, off);
                    float nd2 = fminf(fminf(d2, od2), fmaxf(d1, od1));
                    if (od1 < d1 || (od1 == d1 && oi1 < i1)) { d1 = od1; i1 = oi1; }
                    d2 = nd2;
                }
                if (lc == 0) {
                    const int rr = mf * 16 + la * 4 + rg;
                    idx_lds[w * 32 + rr] = i1;
                    if (d2 - d1 < TAU) {
                        int p2 = atomicAdd(&nflag[w], 1);
                        flagl[w][p2] = rr;
                    }
                }
            }
        }

        // ---- fp64 refinement (wave-local, rare); ILP-2 chain ----
        {
            const int nf = nflag[w];
            for (int f = 0; f < nf; ++f) {
                const int rr = flagl[w][f];
                const int mfr = rr >> 4, r16 = rr & 15;
                if (lc == r16) {
                    #pragma unroll
                    for (int ks = 0; ks < 4; ++ks) {
                        #pragma unroll
                        for (int j = 0; j < 8; ++j)
                            rowbuf[w][la * 8 + ks * 32 + j] =
                                (mfr == 0) ? rres[ks * 8 + j] : rres[32 + ks * 8 + j];
                    }
                }
                asm volatile("s_waitcnt lgkmcnt(0)" ::: "memory");
                __builtin_amdgcn_sched_barrier(0);
                const float4* rf4 = (const float4*)&rowbuf[w][0];
                double bdd = 1e300;
                int bk = 0;
                for (int kk = 0; kk < 16; ++kk) {
                    const int k = l + kk * 64;
                    const float4* bp4 = (const float4*)(cb + ((size_t)qk0 + k) * C_);
                    double s0 = 0.0, s1 = 0.0;
                    for (int c4 = 0; c4 < 32; c4 += 2) {
                        float4 bv0 = bp4[c4], bv1 = bp4[c4 + 1];
                        float4 rv0 = rf4[c4], rv1 = rf4[c4 + 1];
                        double e0 = (double)rv0.x - (double)bv0.x; s0 = fma(e0, e0, s0);
                        double e1 = (double)rv0.y - (double)bv0.y; s0 = fma(e1, e1, s0);
                        double e2 = (double)rv0.z - (double)bv0.z; s0 = fma(e2, e2, s0);
                        double e3 = (double)rv0.w - (double)bv0.w; s0 = fma(e3, e3, s0);
                        double f0 = (double)rv1.x - (double)bv1.x; s1 = fma(f0, f0, s1);
                        double f1 = (double)rv1.y - (double)bv1.y; s1 = fma(f1, f1, s1);
                        double f2 = (double)rv1.z - (double)bv1.z; s1 = fma(f2, f2, s1);
                        double f3 = (double)rv1.w - (double)bv1.w; s1 = fma(f3, f3, s1);
                    }
                    double s = s0 + s1;
                    if (s < bdd || (s == bdd && k < bk)) { bdd = s; bk = k; }
                }
                #pragma unroll
                for (int off = 1; off < 64; off <<= 1) {
                    double od = __shfl_xor(bdd, off);
                    int ok = __shfl_xor(bk, off);
                    if (od < bdd || (od == bdd && ok < bk)) { bdd = od; bk = ok; }
                }
                if (l == 0) idx_lds[w * 32 + rr] = bk;
                asm volatile("s_waitcnt lgkmcnt(0)" ::: "memory");
            }
        }

        // ---- idx out + histogram ----
        if (l < 16) {
            const int k0 = idx_lds[w * 32 + l];
            const int k1 = idx_lds[w * 32 + 16 + l];
            idxws[(size_t)q * M_ + rowbase + l] = k0;
            idxws[(size_t)q * M_ + rowbase + 16 + l] = k1;
            atomicAdd(&counts[qk0 + k0], 1);
            atomicAdd(&counts[qk0 + k1], 1);
        }

        // ---- in-register residual update + loss partial ----
        float sq = 0.f;
        #pragma unroll
        for (int mf = 0; mf < 2; ++mf) {
            const int k = idx_lds[w * 32 + mf * 16 + lc];
            const float* cbr = cb + ((size_t)qk0 + k) * C_ + la * 8;
            #pragma unroll
            for (int ks = 0; ks < 4; ++ks) {
                float4 cv0 = *(const float4*)(cbr + ks * 32);
                float4 cv1 = *(const float4*)(cbr + ks * 32 + 4);
                float cvv[8] = {cv0.x, cv0.y, cv0.z, cv0.w, cv1.x, cv1.y, cv1.z, cv1.w};
                #pragma unroll
                for (int j = 0; j < 8; ++j) {
                    float rv = rres[mf * 32 + ks * 8 + j];
                    float cvj = cvv[j];
                    float dd = rv - cvj;
                    sq += dd * dd;
                    // STE rounding: quant = r + (xd - r); new_res = r - quant
                    rres[mf * 32 + ks * 8 + j] = rv - (rv + (cvj - rv));
                }
            }
        }
        #pragma unroll
        for (int off = 32; off; off >>= 1) sq += __shfl_down(sq, off, 64);
        if (l == 0) wsum[w] = sq;
        __syncthreads();
        if (t == 0) partials[q * NBLK + blockIdx.x] = wsum[0] + wsum[1] + wsum[2] + wsum[3];
        __syncthreads();
    }

    // ---- epilogue: quant = initial - final residual, in-place over res ----
    #pragma unroll
    for (int mf = 0; mf < 2; ++mf) {
        float* ap = res + (size_t)(rowbase + mf * 16 + lc) * C_ + la * 8;
        #pragma unroll
        for (int ks = 0; ks < 4; ++ks) {
            float4 f0 = *(const float4*)(ap + ks * 32);
            float4 f1 = *(const float4*)(ap + ks * 32 + 4);
            float4 o0, o1;
            o0.x = f0.x - rres[mf * 32 + ks * 8 + 0];
            o0.y = f0.y - rres[mf * 32 + ks * 8 + 1];
            o0.z = f0.z - rres[mf * 32 + ks * 8 + 2];
            o0.w = f0.w - rres[mf * 32 + ks * 8 + 3];
            o1.x = f1.x - rres[mf * 32 + ks * 8 + 4];
            o1.y = f1.y - rres[mf * 32 + ks * 8 + 5];
            o1.z = f1.z - rres[mf * 32 + ks * 8 + 6];
            o1.w = f1.w - rres[mf * 32 + ks * 8 + 7];
            *(float4*)(ap + ks * 32) = o0;
            *(float4*)(ap + ks * 32 + 4) = o1;
        }
    }
#undef STAGE
}

// ---------------- scalars: loss + perplexity ----------------
__global__ __launch_bounds__(256) void scalars_kernel(const float* __restrict__ partials,
                                                      const int* __restrict__ counts,
                                                      float* __restrict__ out) {
    __shared__ float red[256];
    const int t = threadIdx.x;
    float loss_acc = 0.f, perp_acc = 0.f;
    for (int q = 0; q < Q_; ++q) {
        float s = 0.f;
        for (int i = t; i < NBLK; i += 256) s += partials[q * NBLK + i];
        red[t] = s;
        __syncthreads();
        for (int o = 128; o; o >>= 1) {
            if (t < o) red[t] += red[t + o];
            __syncthreads();
        }
        if (t == 0) loss_acc += red[0] / (float)(M_ * C_);
        __syncthreads();
    }
    for (int q = 0; q < Q_; ++q) {
        float s = 0.f;
        for (int k = t; k < K_; k += 256) {
            float p = (float)counts[q * K_ + k] / (float)M_;
            s += p * logf(p + 1e-10f);
        }
        red[t] = s;
        __syncthreads();
        for (int o = 128; o; o >>= 1) {
            if (t < o) red[t] += red[t + o];
            __syncthreads();
        }
        if (t == 0) perp_acc += expf(-red[0]);
        __syncthreads();
    }
    if (t == 0) {
        out[OUT_LOSS] = loss_acc / (float)Q_;
        out[OUT_PERP] = perp_acc / (float)Q_;
    }
}

// ---------------- quant (M,C) -> out (B,C,J,T) transpose ----------------
__global__ __launch_bounds__(256) void finalt_kernel(const float* __restrict__ qout,
                                                     float* __restrict__ out) {
    __shared__ float tile[32][33];
    const int tx = threadIdx.x & 31, ty = threadIdx.x >> 5;
    const int jt0 = blockIdx.x * 32;
    const int c0 = blockIdx.y * 32;
    const int b = blockIdx.z;
    const float* qb = qout + ((size_t)b * JT + jt0) * C_ + c0;
    #pragma unroll
    for (int i = 0; i < 4; ++i) {
        int jj = ty + 8 * i;
        tile[jj][tx] = qb[(size_t)jj * C_ + tx];
    }
    __syncthreads();
    float* ob = out + ((size_t)b * C_ + c0) * JT + jt0;
    #pragma unroll
    for (int i = 0; i < 4; ++i) {
        int cc = ty + 8 * i;
        ob[(size_t)cc * JT + tx] = tile[tx][cc];
    }
}

// ---------------- indices (B,J,T,Q) as float ----------------
__global__ __launch_bounds__(256) void idxout_kernel(const int* __restrict__ idxin,
                                                     float* __restrict__ out) {
    int f = blockIdx.x * 256 + threadIdx.x;
    if (f >= M_ * Q_) return;
    int m = f / Q_;
    int q = f - m * Q_;
    out[f] = (float)idxin[q * M_ + m];
}

extern "C" void kernel_launch(void* const* d_in, const int* in_sizes, int n_in,
                              void* d_out, int out_size, void* d_ws, size_t ws_size,
                              hipStream_t stream) {
    const float* x = (const float*)d_in[0];
    const float* cb = (const float*)d_in[1];
    float* out = (float*)d_out;
    char* ws = (char*)d_ws;

    float* res = (float*)ws;                               // 50,331,648 B (in: x^T, out: quant)
    int* idxws = (int*)(ws + 50331648);                    //  2,359,296 B
    float* c2 = (float*)(ws + 52690944);                   //     24,576 B
    int* counts = (int*)(ws + 52715520);                   //     24,576 B
    float* partials = (float*)(ws + 52740096);             //     18,432 B
    unsigned short* cbt = (unsigned short*)(ws + 52758528);// 3,145,728 B

    hipMemsetAsync(counts, 0, Q_ * K_ * sizeof(int), stream);
    c2_kernel<<<1536, 256, 0, stream>>>(cb, c2);
    cbtile_kernel<<<768, 256, 0, stream>>>(cb, cbt);
    transpose_kernel<<<dim3(96, 4, 32), 256, 0, stream>>>(x, res);
    vq_fused_kernel<<<NBLK, 256, 0, stream>>>(res, cb, cbt, c2, idxws, counts, partials);
    scalars_kernel<<<1, 256, 0, stream>>>(partials, counts, out);
    finalt_kernel<<<dim3(96, 4, 32), 256, 0, stream>>>(res, out);
    idxout_kernel<<<2304, 256, 0, stream>>>(idxws, out + OUT_IDX);
}